// Round 11
// baseline (171.749 us; speedup 1.0000x reference)
//
#include <hip/hip_runtime.h>

typedef __attribute__((ext_vector_type(8))) short short8;
typedef __attribute__((ext_vector_type(4))) float f32x4;

static __device__ __forceinline__ unsigned short f2bf(float f) {
  union { float f; unsigned int u; } v; v.f = f;
  unsigned int r = v.u + 0x7FFFu + ((v.u >> 16) & 1u);
  return (unsigned short)(r >> 16);
}
static __device__ __forceinline__ unsigned int pack2(float a, float b) {
  return (unsigned int)f2bf(a) | ((unsigned int)f2bf(b) << 16);
}

// per-wave LDS (shorts): K/O [64][40], V^T [32][72], Q/P [64][40]
#define KO 0
#define VO 2560
#define PO 4864
#define WSTRIDE 7424   // 14848 B per wave

// ---------------- prep: weights->bf16, bias table bf16 [2][2][4][64][64] ----------------
__global__ __launch_bounds__(256) void k_prep(const float* __restrict__ wq,
    const float* __restrict__ wp, const float* __restrict__ tbl,
    unsigned short* __restrict__ dq, unsigned short* __restrict__ dp,
    unsigned short* __restrict__ biasH) {
  const int n = blockIdx.x * 256 + threadIdx.x;
  if (n < 384 * 128) dq[n] = f2bf(wq[n]);
  if (n < 128 * 128) dp[n] = f2bf(wp[n]);
  if (n < 65536) {
    const int j = n & 63, i = (n >> 6) & 63;
    const int h = (n >> 12) & 3, bb = (n >> 14) & 1, aa = (n >> 15) & 1;
    float val;
    if (i >= 49) val = 0.0f;
    else if (j >= 49) val = -1e30f;
    else {
      const int ih = i / 7, iw = i - ih * 7, jh = j / 7, jw = j - jh * 7;
      const int didx = (ih - jh + 6) * 13 + (iw - jw + 6);
      const int irg = (aa ? (ih < 4 ? 3 : 6) : 0) + (bb ? (iw < 4 ? 1 : 2) : 0);
      const int jrg = (aa ? (jh < 4 ? 3 : 6) : 0) + (bb ? (jw < 4 ? 1 : 2) : 0);
      val = tbl[didx * 4 + h] - (irg != jrg ? 100.0f : 0.0f);
    }
    biasH[n] = f2bf(val);
  }
}

// one block per window (4096), 4 waves, wave == head; single barrier before proj
__global__ __launch_bounds__(256, 2) void k_fused(const float* __restrict__ x,
    const unsigned short* __restrict__ Wq, const float* __restrict__ qb,
    const unsigned short* __restrict__ Wp, const float* __restrict__ pb,
    const unsigned short* __restrict__ biasH, float* __restrict__ out) {
  __shared__ __align__(16) unsigned short lds[4 * WSTRIDE];
  const int tid = threadIdx.x;
  const int win = blockIdx.x;
  const int b = win >> 6, wl = win & 63;
  const int wh = wl >> 3, ww = wl & 7;
  const int wv = tid >> 6, ln = tid & 63;
  const int l15 = ln & 15, l4 = ln >> 4;
  unsigned short* W = lds + wv * WSTRIDE;

  // ---- bias prefetch: 16x uint2 (bf16x4 each), hidden under QKV phase ----
  const unsigned short* bmB = biasH
      + ((((wh == 7 ? 2 : 0) + (ww == 7 ? 1 : 0)) * 4 + wv) << 12)
      + l15 * 64 + 4 * l4;
  uint2 bm16[4][4];
#pragma unroll
  for (int mt = 0; mt < 4; ++mt)
#pragma unroll
    for (int nt = 0; nt < 4; ++nt)
      bm16[mt][nt] = *(const uint2*)(bmB + mt * 1024 + nt * 16);

  // A-row pointers (shifted gather); pad rows point at row 0 (finite), zeroed below
  const float* rp[4];
  bool vld[4];
#pragma unroll
  for (int mt = 0; mt < 4; ++mt) {
    const int t = mt * 16 + l15;
    vld[mt] = (t < 49);
    const int tc = vld[mt] ? t : 0;
    const int th = tc / 7, tw = tc - th * 7;
    int sh = wh * 7 + th + 3; if (sh >= 56) sh -= 56;
    int sw = ww * 7 + tw + 3; if (sw >= 56) sw -= 56;
    rp[mt] = x + (((size_t)(b * 56 + sh)) * 56 + sw) * 128;
  }
  int nrow[6];
#pragma unroll
  for (int j = 0; j < 6; ++j)
    nrow[j] = (j >> 1) * 128 + wv * 32 + (j & 1) * 16 + l15;

  const f32x4 z4 = {0.f, 0.f, 0.f, 0.f};
  // ---- QKV: Q,K swapped (lane: t=l15, 4 consecutive d); V unswapped ----
  f32x4 aS[4][4], aV[4][2];
#pragma unroll
  for (int mt = 0; mt < 4; ++mt) {
#pragma unroll
    for (int j = 0; j < 4; ++j) aS[mt][j] = z4;
#pragma unroll
    for (int j = 0; j < 2; ++j) aV[mt][j] = z4;
  }
#pragma unroll
  for (int ks = 0; ks < 4; ++ks) {
    short8 af[4], bf[6];
#pragma unroll
    for (int mt = 0; mt < 4; ++mt) {
      const float4* p = (const float4*)(rp[mt] + ks * 32 + l4 * 8);
      float4 fa = p[0], fb = p[1];
      uint4 u;
      u.x = pack2(fa.x, fa.y); u.y = pack2(fa.z, fa.w);
      u.z = pack2(fb.x, fb.y); u.w = pack2(fb.z, fb.w);
      u.x = vld[mt] ? u.x : 0u; u.y = vld[mt] ? u.y : 0u;
      u.z = vld[mt] ? u.z : 0u; u.w = vld[mt] ? u.w : 0u;
      af[mt] = *(short8*)&u;
    }
#pragma unroll
    for (int j = 0; j < 6; ++j)
      bf[j] = *(const short8*)&Wq[(size_t)nrow[j] * 128 + ks * 32 + l4 * 8];
#pragma unroll
    for (int mt = 0; mt < 4; ++mt) {
#pragma unroll
      for (int j = 0; j < 4; ++j)
        aS[mt][j] = __builtin_amdgcn_mfma_f32_16x16x32_bf16(bf[j], af[mt], aS[mt][j], 0, 0, 0);
#pragma unroll
      for (int j = 0; j < 2; ++j)
        aV[mt][j] = __builtin_amdgcn_mfma_f32_16x16x32_bf16(af[mt], bf[4 + j], aV[mt][j], 0, 0, 0);
    }
  }
  // epilogue: Q -> PO, K -> KO, V^T -> VO (packed b64 writes)
  {
    const float SC = 0.17677669529663687f;
    const float4 bq0 = *(const float4*)(qb + wv * 32 + 4 * l4);
    const float4 bq1 = *(const float4*)(qb + wv * 32 + 16 + 4 * l4);
    const float4 bk0 = *(const float4*)(qb + 128 + wv * 32 + 4 * l4);
    const float4 bk1 = *(const float4*)(qb + 128 + wv * 32 + 16 + 4 * l4);
    const float bv0 = qb[256 + wv * 32 + l15];
    const float bv1 = qb[256 + wv * 32 + 16 + l15];
#pragma unroll
    for (int mt = 0; mt < 4; ++mt) {
      const int t = mt * 16 + l15;
      uint2 u;
      u.x = pack2((aS[mt][0][0] + bq0.x) * SC, (aS[mt][0][1] + bq0.y) * SC);
      u.y = pack2((aS[mt][0][2] + bq0.z) * SC, (aS[mt][0][3] + bq0.w) * SC);
      *(uint2*)&W[PO + t * 40 + 4 * l4] = u;
      u.x = pack2((aS[mt][1][0] + bq1.x) * SC, (aS[mt][1][1] + bq1.y) * SC);
      u.y = pack2((aS[mt][1][2] + bq1.z) * SC, (aS[mt][1][3] + bq1.w) * SC);
      *(uint2*)&W[PO + t * 40 + 16 + 4 * l4] = u;
      u.x = pack2(aS[mt][2][0] + bk0.x, aS[mt][2][1] + bk0.y);
      u.y = pack2(aS[mt][2][2] + bk0.z, aS[mt][2][3] + bk0.w);
      *(uint2*)&W[KO + t * 40 + 4 * l4] = u;
      u.x = pack2(aS[mt][3][0] + bk1.x, aS[mt][3][1] + bk1.y);
      u.y = pack2(aS[mt][3][2] + bk1.z, aS[mt][3][3] + bk1.w);
      *(uint2*)&W[KO + t * 40 + 16 + 4 * l4] = u;
      u.x = pack2(aV[mt][0][0] + bv0, aV[mt][0][1] + bv0);
      u.y = pack2(aV[mt][0][2] + bv0, aV[mt][0][3] + bv0);
      *(uint2*)&W[VO + l15 * 72 + mt * 16 + 4 * l4] = u;
      u.x = pack2(aV[mt][1][0] + bv1, aV[mt][1][1] + bv1);
      u.y = pack2(aV[mt][1][2] + bv1, aV[mt][1][3] + bv1);
      *(uint2*)&W[VO + (16 + l15) * 72 + mt * 16 + 4 * l4] = u;
    }
  }

  // ---- QK^T (S^T layout: lane holds row i = mt*16+l15, cols j = nt*16+4*l4+r) ----
  f32x4 s[4][4];
#pragma unroll
  for (int mt = 0; mt < 4; ++mt)
#pragma unroll
    for (int nt = 0; nt < 4; ++nt) s[mt][nt] = z4;
  {
    short8 qf[4], kf[4];
#pragma unroll
    for (int mt = 0; mt < 4; ++mt)
      qf[mt] = *(const short8*)&W[PO + (mt * 16 + l15) * 40 + l4 * 8];
#pragma unroll
    for (int nt = 0; nt < 4; ++nt)
      kf[nt] = *(const short8*)&W[KO + (nt * 16 + l15) * 40 + l4 * 8];
#pragma unroll
    for (int mt = 0; mt < 4; ++mt)
#pragma unroll
      for (int nt = 0; nt < 4; ++nt)
        s[mt][nt] = __builtin_amdgcn_mfma_f32_16x16x32_bf16(kf[nt], qf[mt], s[mt][nt], 0, 0, 0);
  }

  // ---- softmax: bias from prefetched bf16 regs; max-sub + exact-zero masking ----
  float pmax[4] = {-1e30f, -1e30f, -1e30f, -1e30f};
#pragma unroll
  for (int mt = 0; mt < 4; ++mt) {
#pragma unroll
    for (int nt = 0; nt < 4; ++nt) {
      const uint2 u = bm16[mt][nt];
      s[mt][nt][0] += __uint_as_float(u.x << 16);
      s[mt][nt][1] += __uint_as_float(u.x & 0xFFFF0000u);
      s[mt][nt][2] += __uint_as_float(u.y << 16);
      s[mt][nt][3] += __uint_as_float(u.y & 0xFFFF0000u);
      pmax[mt] = fmaxf(pmax[mt], fmaxf(fmaxf(s[mt][nt][0], s[mt][nt][1]),
                                       fmaxf(s[mt][nt][2], s[mt][nt][3])));
    }
  }
  float inv[4];
#pragma unroll
  for (int mt = 0; mt < 4; ++mt) {
    float m0 = pmax[mt];
    m0 = fmaxf(m0, __shfl_xor(m0, 16));
    m0 = fmaxf(m0, __shfl_xor(m0, 32));
    float sum = 0.0f;
#pragma unroll
    for (int nt = 0; nt < 4; ++nt)
#pragma unroll
      for (int r = 0; r < 4; ++r) {
        const float v = s[mt][nt][r];
        const float e = (v > -1e29f) ? __expf(v - m0) : 0.0f;
        s[mt][nt][r] = e;
        sum += e;
      }
    sum += __shfl_xor(sum, 16);
    sum += __shfl_xor(sum, 32);
    inv[mt] = 1.0f / sum;
  }

  // ---- P pass 0 (j in [0,32)) -> PV pass 0 -> P pass 1 -> PV pass 1 ----
  f32x4 o[4][2];
#pragma unroll
  for (int mt = 0; mt < 4; ++mt)
#pragma unroll
    for (int dt = 0; dt < 2; ++dt) o[mt][dt] = z4;
#pragma unroll
  for (int mt = 0; mt < 4; ++mt) {
    const int i = mt * 16 + l15;
    if (i < 49) {
#pragma unroll
      for (int nt = 0; nt < 2; ++nt) {
        uint2 u;
        u.x = pack2(s[mt][nt][0] * inv[mt], s[mt][nt][1] * inv[mt]);
        u.y = pack2(s[mt][nt][2] * inv[mt], s[mt][nt][3] * inv[mt]);
        *(uint2*)&W[PO + i * 40 + nt * 16 + 4 * l4] = u;
      }
    }
  }
  {
    short8 pa[4], vb[2];
#pragma unroll
    for (int mt = 0; mt < 4; ++mt)
      pa[mt] = *(const short8*)&W[PO + (mt * 16 + l15) * 40 + l4 * 8];
#pragma unroll
    for (int dt = 0; dt < 2; ++dt)
      vb[dt] = *(const short8*)&W[VO + (dt * 16 + l15) * 72 + l4 * 8];
#pragma unroll
    for (int mt = 0; mt < 4; ++mt)
#pragma unroll
      for (int dt = 0; dt < 2; ++dt)
        o[mt][dt] = __builtin_amdgcn_mfma_f32_16x16x32_bf16(vb[dt], pa[mt], o[mt][dt], 0, 0, 0);
  }
#pragma unroll
  for (int mt = 0; mt < 4; ++mt) {
    const int i = mt * 16 + l15;
    if (i < 49) {
#pragma unroll
      for (int nt = 2; nt < 4; ++nt) {
        uint2 u;
        u.x = pack2(s[mt][nt][0] * inv[mt], s[mt][nt][1] * inv[mt]);
        u.y = pack2(s[mt][nt][2] * inv[mt], s[mt][nt][3] * inv[mt]);
        *(uint2*)&W[PO + i * 40 + (nt - 2) * 16 + 4 * l4] = u;
      }
    }
  }
  {
    short8 pa[4], vb[2];
#pragma unroll
    for (int mt = 0; mt < 4; ++mt)
      pa[mt] = *(const short8*)&W[PO + (mt * 16 + l15) * 40 + l4 * 8];
#pragma unroll
    for (int dt = 0; dt < 2; ++dt)
      vb[dt] = *(const short8*)&W[VO + (dt * 16 + l15) * 72 + 32 + l4 * 8];
#pragma unroll
    for (int mt = 0; mt < 4; ++mt)
#pragma unroll
      for (int dt = 0; dt < 2; ++dt)
        o[mt][dt] = __builtin_amdgcn_mfma_f32_16x16x32_bf16(vb[dt], pa[mt], o[mt][dt], 0, 0, 0);
  }
  // stage O (lane: t=l15, 4 consecutive d) -> K buffer (K dead)
#pragma unroll
  for (int mt = 0; mt < 4; ++mt) {
    const int t = mt * 16 + l15;
#pragma unroll
    for (int dt = 0; dt < 2; ++dt) {
      uint2 u;
      u.x = pack2(o[mt][dt][0], o[mt][dt][1]);
      u.y = pack2(o[mt][dt][2], o[mt][dt][3]);
      *(uint2*)&W[KO + t * 40 + dt * 16 + 4 * l4] = u;
    }
  }
  __syncthreads();

  // ---- proj (swapped): lane holds t=l15, 4 consecutive n ----
  const float4 pbv0 = *(const float4*)(pb + wv * 32 + 4 * l4);
  const float4 pbv1 = *(const float4*)(pb + wv * 32 + 16 + 4 * l4);
  f32x4 c2[4][2];
#pragma unroll
  for (int mt = 0; mt < 4; ++mt)
#pragma unroll
    for (int nt = 0; nt < 2; ++nt) c2[mt][nt] = z4;
#pragma unroll
  for (int ks = 0; ks < 4; ++ks) {
    short8 a2[4], bp[2];
#pragma unroll
    for (int mt = 0; mt < 4; ++mt)
      a2[mt] = *(const short8*)&lds[ks * WSTRIDE + KO + (mt * 16 + l15) * 40 + l4 * 8];
#pragma unroll
    for (int nt = 0; nt < 2; ++nt)
      bp[nt] = *(const short8*)&Wp[(size_t)(wv * 32 + nt * 16 + l15) * 128 + ks * 32 + l4 * 8];
#pragma unroll
    for (int mt = 0; mt < 4; ++mt)
#pragma unroll
      for (int nt = 0; nt < 2; ++nt)
        c2[mt][nt] = __builtin_amdgcn_mfma_f32_16x16x32_bf16(bp[nt], a2[mt], c2[mt][nt], 0, 0, 0);
  }
#pragma unroll
  for (int mt = 0; mt < 4; ++mt) {
    const int t = mt * 16 + l15;
    if (t < 49) {
      const int th = t / 7, tw = t - th * 7;
      int y = wh * 7 + th + 3; if (y >= 56) y -= 56;
      int xx = ww * 7 + tw + 3; if (xx >= 56) xx -= 56;
      float* dstp = out + (((size_t)(b * 56 + y)) * 56 + xx) * 128 + wv * 32 + 4 * l4;
      float4 v0, v1;
      v0.x = c2[mt][0][0] + pbv0.x; v0.y = c2[mt][0][1] + pbv0.y;
      v0.z = c2[mt][0][2] + pbv0.z; v0.w = c2[mt][0][3] + pbv0.w;
      *(float4*)(dstp) = v0;
      v1.x = c2[mt][1][0] + pbv1.x; v1.y = c2[mt][1][1] + pbv1.y;
      v1.z = c2[mt][1][2] + pbv1.z; v1.w = c2[mt][1][3] + pbv1.w;
      *(float4*)(dstp + 16) = v1;
    }
  }
}

extern "C" void kernel_launch(void* const* d_in, const int* in_sizes, int n_in,
                              void* d_out, int out_size, void* d_ws, size_t ws_size,
                              hipStream_t stream) {
  const float* x     = (const float*)d_in[0];
  const float* qkvw  = (const float*)d_in[1];
  const float* qkvb  = (const float*)d_in[2];
  const float* projw = (const float*)d_in[3];
  const float* projb = (const float*)d_in[4];
  const float* table = (const float*)d_in[5];
  float* out = (float*)d_out;
  char* ws = (char*)d_ws;
  unsigned short* Wq    = (unsigned short*)ws;             // 98304 B
  unsigned short* Wp    = (unsigned short*)(ws + 98304);   // 32768 B
  unsigned short* biasH = (unsigned short*)(ws + 131072);  // 131072 B

  k_prep<<<dim3(256), dim3(256), 0, stream>>>(qkvw, projw, table, Wq, Wp, biasH);
  k_fused<<<dim3(4096), dim3(256), 0, stream>>>(x, Wq, qkvb, Wp, projb, biasH, out);
}

// Round 12
// 167.542 us; speedup vs baseline: 1.0251x; 1.0251x over previous
//
#include <hip/hip_runtime.h>

typedef __attribute__((ext_vector_type(8))) short short8;
typedef __attribute__((ext_vector_type(4))) float f32x4;

static __device__ __forceinline__ unsigned short f2bf(float f) {
  union { float f; unsigned int u; } v; v.f = f;
  unsigned int r = v.u + 0x7FFFu + ((v.u >> 16) & 1u);
  return (unsigned short)(r >> 16);
}
static __device__ __forceinline__ unsigned int pack2(float a, float b) {
  return (unsigned int)f2bf(a) | ((unsigned int)f2bf(b) << 16);
}

// per-wave LDS (shorts): K/O [64][40], V^T [32][72], Q/P [64][40]
#define KO 0
#define VO 2560
#define PO 4864
#define WSTRIDE 7424   // 14848 B per wave

// ---------------- prep: weights->bf16, bias table bf16 [2][2][4][64][64] ----------------
__global__ __launch_bounds__(256) void k_prep(const float* __restrict__ wq,
    const float* __restrict__ wp, const float* __restrict__ tbl,
    unsigned short* __restrict__ dq, unsigned short* __restrict__ dp,
    unsigned short* __restrict__ biasH) {
  const int n = blockIdx.x * 256 + threadIdx.x;
  if (n < 384 * 128) dq[n] = f2bf(wq[n]);
  if (n < 128 * 128) dp[n] = f2bf(wp[n]);
  if (n < 65536) {
    const int j = n & 63, i = (n >> 6) & 63;
    const int h = (n >> 12) & 3, bb = (n >> 14) & 1, aa = (n >> 15) & 1;
    float val;
    if (i >= 49) val = 0.0f;
    else if (j >= 49) val = -1e30f;
    else {
      const int ih = i / 7, iw = i - ih * 7, jh = j / 7, jw = j - jh * 7;
      const int didx = (ih - jh + 6) * 13 + (iw - jw + 6);
      const int irg = (aa ? (ih < 4 ? 3 : 6) : 0) + (bb ? (iw < 4 ? 1 : 2) : 0);
      const int jrg = (aa ? (jh < 4 ? 3 : 6) : 0) + (bb ? (jw < 4 ? 1 : 2) : 0);
      val = tbl[didx * 4 + h] - (irg != jrg ? 100.0f : 0.0f);
    }
    biasH[n] = f2bf(val);
  }
}

// ---------------- prepx: x -> bf16, window-partitioned + pre-shifted ----------------
// xw[win][t][c], win=0..4095, t=0..48, c=0..127; 8 channels per thread
__global__ __launch_bounds__(256) void k_prepx(const float* __restrict__ x,
    unsigned short* __restrict__ xw) {
  const int idx = blockIdx.x * 256 + threadIdx.x;   // unit = 8 channels
  const int row = idx >> 4;                          // (win,t), 200704 rows
  const int c8 = idx & 15;
  const int win = row / 49;
  const int t = row - win * 49;
  const int b = win >> 6, wl = win & 63;
  const int wh = wl >> 3, ww = wl & 7;
  const int th = t / 7, tw = t - th * 7;
  int sh = wh * 7 + th + 3; if (sh >= 56) sh -= 56;
  int sw = ww * 7 + tw + 3; if (sw >= 56) sw -= 56;
  const float4* src = (const float4*)(x + (((size_t)(b * 56 + sh)) * 56 + sw) * 128 + c8 * 8);
  float4 fa = src[0], fb = src[1];
  uint4 u;
  u.x = pack2(fa.x, fa.y); u.y = pack2(fa.z, fa.w);
  u.z = pack2(fb.x, fb.y); u.w = pack2(fb.z, fb.w);
  *(uint4*)(xw + (size_t)row * 128 + c8 * 8) = u;
}

// one block per window (4096), 4 waves, wave == head; single barrier before proj
__global__ __launch_bounds__(256, 2) void k_fused(const unsigned short* __restrict__ xw,
    const unsigned short* __restrict__ Wq, const float* __restrict__ qb,
    const unsigned short* __restrict__ Wp, const float* __restrict__ pb,
    const unsigned short* __restrict__ biasH, float* __restrict__ out) {
  __shared__ __align__(16) unsigned short lds[4 * WSTRIDE];
  const int tid = threadIdx.x;
  const int win = blockIdx.x;
  const int b = win >> 6, wl = win & 63;
  const int wh = wl >> 3, ww = wl & 7;
  const int wv = tid >> 6, ln = tid & 63;
  const int l15 = ln & 15, l4 = ln >> 4;
  unsigned short* W = lds + wv * WSTRIDE;

  // ---- bias prefetch: 16x uint2 (bf16x4 each), hidden under QKV phase ----
  const unsigned short* bmB = biasH
      + ((((wh == 7 ? 2 : 0) + (ww == 7 ? 1 : 0)) * 4 + wv) << 12)
      + l15 * 64 + 4 * l4;
  uint2 bm16[4][4];
#pragma unroll
  for (int mt = 0; mt < 4; ++mt)
#pragma unroll
    for (int nt = 0; nt < 4; ++nt)
      bm16[mt][nt] = *(const uint2*)(bmB + mt * 1024 + nt * 16);

  // A-row pointers into pre-gathered bf16 xw; pad rows -> row 0 (finite), zeroed below
  const unsigned short* rp[4];
  bool vld[4];
#pragma unroll
  for (int mt = 0; mt < 4; ++mt) {
    const int t = mt * 16 + l15;
    vld[mt] = (t < 49);
    rp[mt] = xw + ((size_t)win * 49 + (vld[mt] ? t : 0)) * 128;
  }
  int nrow[6];
#pragma unroll
  for (int j = 0; j < 6; ++j)
    nrow[j] = (j >> 1) * 128 + wv * 32 + (j & 1) * 16 + l15;

  const f32x4 z4 = {0.f, 0.f, 0.f, 0.f};
  // ---- QKV: Q,K swapped (lane: t=l15, 4 consecutive d); V unswapped ----
  f32x4 aS[4][4], aV[4][2];
#pragma unroll
  for (int mt = 0; mt < 4; ++mt) {
#pragma unroll
    for (int j = 0; j < 4; ++j) aS[mt][j] = z4;
#pragma unroll
    for (int j = 0; j < 2; ++j) aV[mt][j] = z4;
  }
#pragma unroll
  for (int ks = 0; ks < 4; ++ks) {
    short8 af[4], bf[6];
#pragma unroll
    for (int mt = 0; mt < 4; ++mt) {
      uint4 u = *(const uint4*)(rp[mt] + ks * 32 + l4 * 8);
      u.x = vld[mt] ? u.x : 0u; u.y = vld[mt] ? u.y : 0u;
      u.z = vld[mt] ? u.z : 0u; u.w = vld[mt] ? u.w : 0u;
      af[mt] = *(short8*)&u;
    }
#pragma unroll
    for (int j = 0; j < 6; ++j)
      bf[j] = *(const short8*)&Wq[(size_t)nrow[j] * 128 + ks * 32 + l4 * 8];
#pragma unroll
    for (int mt = 0; mt < 4; ++mt) {
#pragma unroll
      for (int j = 0; j < 4; ++j)
        aS[mt][j] = __builtin_amdgcn_mfma_f32_16x16x32_bf16(bf[j], af[mt], aS[mt][j], 0, 0, 0);
#pragma unroll
      for (int j = 0; j < 2; ++j)
        aV[mt][j] = __builtin_amdgcn_mfma_f32_16x16x32_bf16(af[mt], bf[4 + j], aV[mt][j], 0, 0, 0);
    }
  }
  // epilogue: Q -> PO, K -> KO, V^T -> VO (packed b64 writes)
  {
    const float SC = 0.17677669529663687f;
    const float4 bq0 = *(const float4*)(qb + wv * 32 + 4 * l4);
    const float4 bq1 = *(const float4*)(qb + wv * 32 + 16 + 4 * l4);
    const float4 bk0 = *(const float4*)(qb + 128 + wv * 32 + 4 * l4);
    const float4 bk1 = *(const float4*)(qb + 128 + wv * 32 + 16 + 4 * l4);
    const float bv0 = qb[256 + wv * 32 + l15];
    const float bv1 = qb[256 + wv * 32 + 16 + l15];
#pragma unroll
    for (int mt = 0; mt < 4; ++mt) {
      const int t = mt * 16 + l15;
      uint2 u;
      u.x = pack2((aS[mt][0][0] + bq0.x) * SC, (aS[mt][0][1] + bq0.y) * SC);
      u.y = pack2((aS[mt][0][2] + bq0.z) * SC, (aS[mt][0][3] + bq0.w) * SC);
      *(uint2*)&W[PO + t * 40 + 4 * l4] = u;
      u.x = pack2((aS[mt][1][0] + bq1.x) * SC, (aS[mt][1][1] + bq1.y) * SC);
      u.y = pack2((aS[mt][1][2] + bq1.z) * SC, (aS[mt][1][3] + bq1.w) * SC);
      *(uint2*)&W[PO + t * 40 + 16 + 4 * l4] = u;
      u.x = pack2(aS[mt][2][0] + bk0.x, aS[mt][2][1] + bk0.y);
      u.y = pack2(aS[mt][2][2] + bk0.z, aS[mt][2][3] + bk0.w);
      *(uint2*)&W[KO + t * 40 + 4 * l4] = u;
      u.x = pack2(aS[mt][3][0] + bk1.x, aS[mt][3][1] + bk1.y);
      u.y = pack2(aS[mt][3][2] + bk1.z, aS[mt][3][3] + bk1.w);
      *(uint2*)&W[KO + t * 40 + 16 + 4 * l4] = u;
      u.x = pack2(aV[mt][0][0] + bv0, aV[mt][0][1] + bv0);
      u.y = pack2(aV[mt][0][2] + bv0, aV[mt][0][3] + bv0);
      *(uint2*)&W[VO + l15 * 72 + mt * 16 + 4 * l4] = u;
      u.x = pack2(aV[mt][1][0] + bv1, aV[mt][1][1] + bv1);
      u.y = pack2(aV[mt][1][2] + bv1, aV[mt][1][3] + bv1);
      *(uint2*)&W[VO + (16 + l15) * 72 + mt * 16 + 4 * l4] = u;
    }
  }

  // ---- QK^T (S^T layout: lane holds row i = mt*16+l15, cols j = nt*16+4*l4+r) ----
  f32x4 s[4][4];
#pragma unroll
  for (int mt = 0; mt < 4; ++mt)
#pragma unroll
    for (int nt = 0; nt < 4; ++nt) s[mt][nt] = z4;
  {
    short8 qf[4], kf[4];
#pragma unroll
    for (int mt = 0; mt < 4; ++mt)
      qf[mt] = *(const short8*)&W[PO + (mt * 16 + l15) * 40 + l4 * 8];
#pragma unroll
    for (int nt = 0; nt < 4; ++nt)
      kf[nt] = *(const short8*)&W[KO + (nt * 16 + l15) * 40 + l4 * 8];
#pragma unroll
    for (int mt = 0; mt < 4; ++mt)
#pragma unroll
      for (int nt = 0; nt < 4; ++nt)
        s[mt][nt] = __builtin_amdgcn_mfma_f32_16x16x32_bf16(kf[nt], qf[mt], s[mt][nt], 0, 0, 0);
  }

  // ---- softmax: bias from prefetched bf16 regs; max-sub + exact-zero masking ----
  float pmax[4] = {-1e30f, -1e30f, -1e30f, -1e30f};
#pragma unroll
  for (int mt = 0; mt < 4; ++mt) {
#pragma unroll
    for (int nt = 0; nt < 4; ++nt) {
      const uint2 u = bm16[mt][nt];
      s[mt][nt][0] += __uint_as_float(u.x << 16);
      s[mt][nt][1] += __uint_as_float(u.x & 0xFFFF0000u);
      s[mt][nt][2] += __uint_as_float(u.y << 16);
      s[mt][nt][3] += __uint_as_float(u.y & 0xFFFF0000u);
      pmax[mt] = fmaxf(pmax[mt], fmaxf(fmaxf(s[mt][nt][0], s[mt][nt][1]),
                                       fmaxf(s[mt][nt][2], s[mt][nt][3])));
    }
  }
  float inv[4];
#pragma unroll
  for (int mt = 0; mt < 4; ++mt) {
    float m0 = pmax[mt];
    m0 = fmaxf(m0, __shfl_xor(m0, 16));
    m0 = fmaxf(m0, __shfl_xor(m0, 32));
    float sum = 0.0f;
#pragma unroll
    for (int nt = 0; nt < 4; ++nt)
#pragma unroll
      for (int r = 0; r < 4; ++r) {
        const float v = s[mt][nt][r];
        const float e = (v > -1e29f) ? __expf(v - m0) : 0.0f;
        s[mt][nt][r] = e;
        sum += e;
      }
    sum += __shfl_xor(sum, 16);
    sum += __shfl_xor(sum, 32);
    inv[mt] = 1.0f / sum;
  }

  // ---- P pass 0 (j in [0,32)) -> PV pass 0 -> P pass 1 -> PV pass 1 ----
  f32x4 o[4][2];
#pragma unroll
  for (int mt = 0; mt < 4; ++mt)
#pragma unroll
    for (int dt = 0; dt < 2; ++dt) o[mt][dt] = z4;
#pragma unroll
  for (int mt = 0; mt < 4; ++mt) {
    const int i = mt * 16 + l15;
    if (i < 49) {
#pragma unroll
      for (int nt = 0; nt < 2; ++nt) {
        uint2 u;
        u.x = pack2(s[mt][nt][0] * inv[mt], s[mt][nt][1] * inv[mt]);
        u.y = pack2(s[mt][nt][2] * inv[mt], s[mt][nt][3] * inv[mt]);
        *(uint2*)&W[PO + i * 40 + nt * 16 + 4 * l4] = u;
      }
    }
  }
  {
    short8 pa[4], vb[2];
#pragma unroll
    for (int mt = 0; mt < 4; ++mt)
      pa[mt] = *(const short8*)&W[PO + (mt * 16 + l15) * 40 + l4 * 8];
#pragma unroll
    for (int dt = 0; dt < 2; ++dt)
      vb[dt] = *(const short8*)&W[VO + (dt * 16 + l15) * 72 + l4 * 8];
#pragma unroll
    for (int mt = 0; mt < 4; ++mt)
#pragma unroll
      for (int dt = 0; dt < 2; ++dt)
        o[mt][dt] = __builtin_amdgcn_mfma_f32_16x16x32_bf16(vb[dt], pa[mt], o[mt][dt], 0, 0, 0);
  }
#pragma unroll
  for (int mt = 0; mt < 4; ++mt) {
    const int i = mt * 16 + l15;
    if (i < 49) {
#pragma unroll
      for (int nt = 2; nt < 4; ++nt) {
        uint2 u;
        u.x = pack2(s[mt][nt][0] * inv[mt], s[mt][nt][1] * inv[mt]);
        u.y = pack2(s[mt][nt][2] * inv[mt], s[mt][nt][3] * inv[mt]);
        *(uint2*)&W[PO + i * 40 + (nt - 2) * 16 + 4 * l4] = u;
      }
    }
  }
  {
    short8 pa[4], vb[2];
#pragma unroll
    for (int mt = 0; mt < 4; ++mt)
      pa[mt] = *(const short8*)&W[PO + (mt * 16 + l15) * 40 + l4 * 8];
#pragma unroll
    for (int dt = 0; dt < 2; ++dt)
      vb[dt] = *(const short8*)&W[VO + (dt * 16 + l15) * 72 + 32 + l4 * 8];
#pragma unroll
    for (int mt = 0; mt < 4; ++mt)
#pragma unroll
      for (int dt = 0; dt < 2; ++dt)
        o[mt][dt] = __builtin_amdgcn_mfma_f32_16x16x32_bf16(vb[dt], pa[mt], o[mt][dt], 0, 0, 0);
  }
  // stage O (lane: t=l15, 4 consecutive d) -> K buffer (K dead)
#pragma unroll
  for (int mt = 0; mt < 4; ++mt) {
    const int t = mt * 16 + l15;
#pragma unroll
    for (int dt = 0; dt < 2; ++dt) {
      uint2 u;
      u.x = pack2(o[mt][dt][0], o[mt][dt][1]);
      u.y = pack2(o[mt][dt][2], o[mt][dt][3]);
      *(uint2*)&W[KO + t * 40 + dt * 16 + 4 * l4] = u;
    }
  }
  __syncthreads();

  // ---- proj (swapped): lane holds t=l15, 4 consecutive n ----
  const float4 pbv0 = *(const float4*)(pb + wv * 32 + 4 * l4);
  const float4 pbv1 = *(const float4*)(pb + wv * 32 + 16 + 4 * l4);
  f32x4 c2[4][2];
#pragma unroll
  for (int mt = 0; mt < 4; ++mt)
#pragma unroll
    for (int nt = 0; nt < 2; ++nt) c2[mt][nt] = z4;
#pragma unroll
  for (int ks = 0; ks < 4; ++ks) {
    short8 a2[4], bp[2];
#pragma unroll
    for (int mt = 0; mt < 4; ++mt)
      a2[mt] = *(const short8*)&lds[ks * WSTRIDE + KO + (mt * 16 + l15) * 40 + l4 * 8];
#pragma unroll
    for (int nt = 0; nt < 2; ++nt)
      bp[nt] = *(const short8*)&Wp[(size_t)(wv * 32 + nt * 16 + l15) * 128 + ks * 32 + l4 * 8];
#pragma unroll
    for (int mt = 0; mt < 4; ++mt)
#pragma unroll
      for (int nt = 0; nt < 2; ++nt)
        c2[mt][nt] = __builtin_amdgcn_mfma_f32_16x16x32_bf16(bp[nt], a2[mt], c2[mt][nt], 0, 0, 0);
  }
#pragma unroll
  for (int mt = 0; mt < 4; ++mt) {
    const int t = mt * 16 + l15;
    if (t < 49) {
      const int th = t / 7, tw = t - th * 7;
      int y = wh * 7 + th + 3; if (y >= 56) y -= 56;
      int xx = ww * 7 + tw + 3; if (xx >= 56) xx -= 56;
      float* dstp = out + (((size_t)(b * 56 + y)) * 56 + xx) * 128 + wv * 32 + 4 * l4;
      float4 v0, v1;
      v0.x = c2[mt][0][0] + pbv0.x; v0.y = c2[mt][0][1] + pbv0.y;
      v0.z = c2[mt][0][2] + pbv0.z; v0.w = c2[mt][0][3] + pbv0.w;
      *(float4*)(dstp) = v0;
      v1.x = c2[mt][1][0] + pbv1.x; v1.y = c2[mt][1][1] + pbv1.y;
      v1.z = c2[mt][1][2] + pbv1.z; v1.w = c2[mt][1][3] + pbv1.w;
      *(float4*)(dstp + 16) = v1;
    }
  }
}

extern "C" void kernel_launch(void* const* d_in, const int* in_sizes, int n_in,
                              void* d_out, int out_size, void* d_ws, size_t ws_size,
                              hipStream_t stream) {
  const float* x     = (const float*)d_in[0];
  const float* qkvw  = (const float*)d_in[1];
  const float* qkvb  = (const float*)d_in[2];
  const float* projw = (const float*)d_in[3];
  const float* projb = (const float*)d_in[4];
  const float* table = (const float*)d_in[5];
  float* out = (float*)d_out;
  char* ws = (char*)d_ws;
  unsigned short* xw    = (unsigned short*)ws;                  // 51380224 B
  unsigned short* Wq    = (unsigned short*)(ws + 51380224);     // 98304 B
  unsigned short* Wp    = (unsigned short*)(ws + 51478528);     // 32768 B
  unsigned short* biasH = (unsigned short*)(ws + 51511296);     // 131072 B

  k_prep<<<dim3(256), dim3(256), 0, stream>>>(qkvw, projw, table, Wq, Wp, biasH);
  k_prepx<<<dim3(12544), dim3(256), 0, stream>>>(x, xw);
  k_fused<<<dim3(4096), dim3(256), 0, stream>>>(xw, Wq, qkvb, Wp, projb, biasH, out);
}